// Round 3
// baseline (322.558 us; speedup 1.0000x reference)
//
#include <hip/hip_runtime.h>

#define N_NODES 50000
#define N_EDGES 800000
#define TOT (N_EDGES + N_NODES)

typedef __attribute__((ext_vector_type(8))) short short8;
typedef __attribute__((ext_vector_type(4))) float floatx4;

// ---- workspace layout (bytes, 256-aligned) ----
#define O_DEG   0UL          // int[N]
#define O_PTR   200192UL     // int[N]
#define O_FILL  400384UL     // int[N]
#define O_BSUM  600576UL     // int[64]
#define O_BOFF  600832UL     // int[64]
#define O_FLAG  601088UL     // int[2]: [1]=indices-are-int64
#define O_DINV  601344UL     // float[N]
#define O_ESRC  801536UL     // int[TOT]
#define O_W1H   4201728UL    // bf16[128*128] hi
#define O_W1L   4234496UL    // bf16[128*128] lo
#define O_W2H   4267264UL    // bf16[64*128] hi
#define O_W2L   4283648UL    // bf16[64*128] lo
#define O_XS    4300032UL    // bf16[N*128]
#define O_YR    17100032UL   // bf16[N*128]
// end: 29900032 bytes

__device__ __forceinline__ float bf2f(unsigned short u) {
    union { unsigned u; float f; } v; v.u = ((unsigned)u) << 16; return v.f;
}
__device__ __forceinline__ unsigned short f2bf(float f) {
    union { float f; unsigned u; } v; v.f = f;
    unsigned u = v.u;
    unsigned r = u + 0x7fffu + ((u >> 16) & 1u);   // RNE
    return (unsigned short)(r >> 16);
}
// split f32 -> hi (truncated bf16) + lo (bf16 of remainder); hi+lo ~ 2^-17 rel
__device__ __forceinline__ void bsplit(float f, short& hi, short& lo) {
    union { float f; unsigned u; } v; v.f = f;
    unsigned short h = (unsigned short)(v.u >> 16);
    float rem = f - bf2f(h);
    hi = (short)h; lo = (short)f2bf(rem);
}

// index-width probe: int64 => odd 32-bit words all zero (values < 2^31)
__global__ void k_probe(const unsigned* ei_raw, int* flags) {
    if (threadIdx.x == 0) {
        int zc = 0;
        for (int i = 0; i < 64; ++i)
            if (ei_raw[2 * i + 1] == 0u) ++zc;
        flags[1] = (zc >= 60) ? 1 : 0;
        flags[0] = 0;
    }
}

__global__ void k_init(int* deg) {
    int i = blockIdx.x * 256 + threadIdx.x;
    if (i < N_NODES) deg[i] = 1;                   // self-loop
}

__global__ void k_count(const int* ei, const int* flags, int* deg) {
    int e = blockIdx.x * 256 + threadIdx.x;
    if (e >= N_EDGES) return;
    int c = flags[1] ? ei[2 * (N_EDGES + e)] : ei[N_EDGES + e];
    atomicAdd(&deg[c], 1);
}

// 2-level exclusive scan over deg[N] -> ptr[N]
__global__ void k_scan1(const int* deg, int* ptr, int* bsum) {
    __shared__ int sm[256];
    int t = threadIdx.x;
    int base = blockIdx.x * 1024 + t * 4;
    int v[4]; int ts = 0;
#pragma unroll
    for (int j = 0; j < 4; ++j) { int idx = base + j; v[j] = (idx < N_NODES) ? deg[idx] : 0; ts += v[j]; }
    sm[t] = ts; __syncthreads();
    for (int off = 1; off < 256; off <<= 1) {
        int x = (t >= off) ? sm[t - off] : 0;
        __syncthreads();
        sm[t] += x;
        __syncthreads();
    }
    int run = sm[t] - ts;
#pragma unroll
    for (int j = 0; j < 4; ++j) { int idx = base + j; if (idx < N_NODES) ptr[idx] = run; run += v[j]; }
    if (t == 255) bsum[blockIdx.x] = sm[255];
}

#define NB_SCAN 49
__global__ void k_scan2(const int* bsum, int* boff) {
    if (threadIdx.x == 0) {
        int run = 0;
        for (int b = 0; b < NB_SCAN; ++b) { int t = bsum[b]; boff[b] = run; run += t; }
    }
}

__global__ void k_scan3(const int* deg, int* ptr, int* fill, float* dinv, const int* boff) {
    int i = blockIdx.x * 256 + threadIdx.x;
    if (i < N_NODES) {
        int p = ptr[i] + boff[i >> 10];
        ptr[i] = p; fill[i] = p;
        dinv[i] = rsqrtf((float)deg[i]);
    }
}

__global__ void k_scatter(const int* ei, const int* flags, int* fill, int* esrc) {
    int i = blockIdx.x * 256 + threadIdx.x;
    if (i >= TOT) return;
    int r, c;
    if (i < N_EDGES) {
        if (flags[1]) { r = ei[2 * i]; c = ei[2 * (N_EDGES + i)]; }
        else          { r = ei[i];     c = ei[N_EDGES + i]; }
    } else {
        r = c = i - N_EDGES;
    }
    int slot = atomicAdd(&fill[c], 1);
    esrc[slot] = r;
}

// W1[n*128+k] = split(Wg[k*128+n]); W2[n*128+k] = split(Wf[k*64+n])
__global__ void k_transpose(const float* Wg, const float* Wf,
                            ushort* W1h, ushort* W1l, ushort* W2h, ushort* W2l) {
    int i = blockIdx.x * 256 + threadIdx.x;
    if (i < 128 * 128) {
        int n = i >> 7, k = i & 127;
        short hi, lo; bsplit(Wg[k * 128 + n], hi, lo);
        W1h[i] = (ushort)hi; W1l[i] = (ushort)lo;
    }
    if (i < 64 * 128) {
        int n = i >> 7, k = i & 127;
        short hi, lo; bsplit(Wf[k * 64 + n], hi, lo);
        W2h[i] = (ushort)hi; W2l[i] = (ushort)lo;
    }
}

// xs[r][n] = bf16( (h @ Wg)[r][n] * dinv[r] )   (split-bf16, ~f32-exact)
__global__ __launch_bounds__(256) void k_gemm1(const float* __restrict__ h,
                                               const ushort* __restrict__ W1h,
                                               const ushort* __restrict__ W1l,
                                               const float* __restrict__ dinv,
                                               ushort* __restrict__ xs) {
    int wave = threadIdx.x >> 6;
    int lane = threadIdx.x & 63;
    int rowbase = (blockIdx.x * 4 + wave) * 16;
    if (rowbase >= N_NODES) return;
    int quad = lane >> 4;
    int mrow = rowbase + (lane & 15);
    int mr = mrow < N_NODES ? mrow : N_NODES - 1;  // clamp loads; stores guarded
    short8 ah[4], al[4];
#pragma unroll
    for (int kk = 0; kk < 4; ++kk) {
        const float* p = h + (size_t)mr * 128 + kk * 32 + quad * 8;
        short8 th, tl;
#pragma unroll
        for (int j = 0; j < 8; ++j) { short hi, lo; bsplit(p[j], hi, lo); th[j] = hi; tl[j] = lo; }
        ah[kk] = th; al[kk] = tl;
    }
    float dv[4];
#pragma unroll
    for (int i = 0; i < 4; ++i) {
        int r = rowbase + quad * 4 + i;
        dv[i] = (r < N_NODES) ? dinv[r] : 0.f;
    }
#pragma unroll
    for (int nt = 0; nt < 8; ++nt) {
        floatx4 acc = {0.f, 0.f, 0.f, 0.f};
        int n = nt * 16 + (lane & 15);
#pragma unroll
        for (int kk = 0; kk < 4; ++kk) {
            const ushort* bp = W1h + n * 128 + kk * 32 + quad * 8;
            short8 bh = *(const short8*)bp;
            short8 bl = *(const short8*)(W1l + n * 128 + kk * 32 + quad * 8);
            acc = __builtin_amdgcn_mfma_f32_16x16x32_bf16(ah[kk], bh, acc, 0, 0, 0);
            acc = __builtin_amdgcn_mfma_f32_16x16x32_bf16(al[kk], bh, acc, 0, 0, 0);
            acc = __builtin_amdgcn_mfma_f32_16x16x32_bf16(ah[kk], bl, acc, 0, 0, 0);
        }
#pragma unroll
        for (int i = 0; i < 4; ++i) {
            int r = rowbase + quad * 4 + i;
            if (r < N_NODES) xs[(size_t)r * 128 + n] = f2bf(acc[i] * dv[i]);
        }
    }
}

// one wave per node: yr[v] = bf16(relu(dinv[v]*sum(xs[src]) + b_gcn))
__global__ __launch_bounds__(256) void k_agg(const ushort* __restrict__ xs,
                                             const int* __restrict__ ptr,
                                             const int* __restrict__ esrc,
                                             const float* __restrict__ dinv,
                                             const float* __restrict__ bg,
                                             ushort* __restrict__ yr) {
    int wid = (blockIdx.x * 256 + threadIdx.x) >> 6;
    int lane = threadIdx.x & 63;
    if (wid >= N_NODES) return;
    int p0 = ptr[wid];
    int p1 = (wid + 1 < N_NODES) ? ptr[wid + 1] : TOT;
    float a0 = 0.f, a1 = 0.f;
    for (int i = p0; i < p1; ++i) {
        int s = esrc[i];
        unsigned u = *(const unsigned*)(xs + (size_t)s * 128 + lane * 2);
        a0 += bf2f((unsigned short)u);
        a1 += bf2f((unsigned short)(u >> 16));
    }
    float sc = dinv[wid];
    float r0 = fmaxf(fmaf(a0, sc, bg[lane * 2]), 0.f);
    float r1 = fmaxf(fmaf(a1, sc, bg[lane * 2 + 1]), 0.f);
    unsigned o = ((unsigned)f2bf(r1) << 16) | (unsigned)f2bf(r0);
    *(unsigned*)(yr + (size_t)wid * 128 + lane * 2) = o;
}

// out[r][n] = f32( (yr @ Wf)[r][n] + b_fc[n] )   (A=yr exact bf16; B split)
__global__ __launch_bounds__(256) void k_gemm2(const ushort* __restrict__ yr,
                                               const ushort* __restrict__ W2h,
                                               const ushort* __restrict__ W2l,
                                               const float* __restrict__ bfc,
                                               float* __restrict__ out) {
    int wave = threadIdx.x >> 6;
    int lane = threadIdx.x & 63;
    int rowbase = (blockIdx.x * 4 + wave) * 16;
    if (rowbase >= N_NODES) return;
    int quad = lane >> 4;
    int mrow = rowbase + (lane & 15);
    int mr = mrow < N_NODES ? mrow : N_NODES - 1;
    short8 a[4];
#pragma unroll
    for (int kk = 0; kk < 4; ++kk)
        a[kk] = *(const short8*)(yr + (size_t)mr * 128 + kk * 32 + quad * 8);
#pragma unroll
    for (int nt = 0; nt < 4; ++nt) {
        floatx4 acc = {0.f, 0.f, 0.f, 0.f};
        int n = nt * 16 + (lane & 15);
#pragma unroll
        for (int kk = 0; kk < 4; ++kk) {
            short8 bh = *(const short8*)(W2h + n * 128 + kk * 32 + quad * 8);
            short8 bl = *(const short8*)(W2l + n * 128 + kk * 32 + quad * 8);
            acc = __builtin_amdgcn_mfma_f32_16x16x32_bf16(a[kk], bh, acc, 0, 0, 0);
            acc = __builtin_amdgcn_mfma_f32_16x16x32_bf16(a[kk], bl, acc, 0, 0, 0);
        }
        float bias = bfc[n];
#pragma unroll
        for (int i = 0; i < 4; ++i) {
            int r = rowbase + quad * 4 + i;
            if (r < N_NODES) out[(size_t)r * 64 + n] = acc[i] + bias;
        }
    }
}

extern "C" void kernel_launch(void* const* d_in, const int* in_sizes, int n_in,
                              void* d_out, int out_size, void* d_ws, size_t ws_size,
                              hipStream_t stream) {
    (void)in_sizes; (void)n_in; (void)out_size; (void)ws_size;
    const float* h  = (const float*)d_in[0];
    const int*   ei = (const int*)d_in[1];
    const float* Wg = (const float*)d_in[2];
    const float* bg = (const float*)d_in[3];
    const float* Wf = (const float*)d_in[4];
    const float* bf = (const float*)d_in[5];
    float* out = (float*)d_out;

    char* ws = (char*)d_ws;
    int*    deg   = (int*)(ws + O_DEG);
    int*    ptr   = (int*)(ws + O_PTR);
    int*    fill  = (int*)(ws + O_FILL);
    int*    bsum  = (int*)(ws + O_BSUM);
    int*    boff  = (int*)(ws + O_BOFF);
    int*    flags = (int*)(ws + O_FLAG);
    float*  dinv  = (float*)(ws + O_DINV);
    int*    esrc  = (int*)(ws + O_ESRC);
    ushort* W1h   = (ushort*)(ws + O_W1H);
    ushort* W1l   = (ushort*)(ws + O_W1L);
    ushort* W2h   = (ushort*)(ws + O_W2H);
    ushort* W2l   = (ushort*)(ws + O_W2L);
    ushort* xs    = (ushort*)(ws + O_XS);
    ushort* yr    = (ushort*)(ws + O_YR);

    k_probe<<<1, 64, 0, stream>>>((const unsigned*)ei, flags);
    k_init<<<(N_NODES + 255) / 256, 256, 0, stream>>>(deg);
    k_count<<<(N_EDGES + 255) / 256, 256, 0, stream>>>(ei, flags, deg);
    k_scan1<<<NB_SCAN, 256, 0, stream>>>(deg, ptr, bsum);
    k_scan2<<<1, 64, 0, stream>>>(bsum, boff);
    k_scan3<<<(N_NODES + 255) / 256, 256, 0, stream>>>(deg, ptr, fill, dinv, boff);
    k_scatter<<<(TOT + 255) / 256, 256, 0, stream>>>(ei, flags, fill, esrc);
    k_transpose<<<(128 * 128 + 255) / 256, 256, 0, stream>>>(Wg, Wf, W1h, W1l, W2h, W2l);
    k_gemm1<<<(N_NODES + 63) / 64, 256, 0, stream>>>(h, W1h, W1l, dinv, xs);
    k_agg<<<(N_NODES + 3) / 4, 256, 0, stream>>>(xs, ptr, esrc, dinv, bg, yr);
    k_gemm2<<<(N_NODES + 63) / 64, 256, 0, stream>>>(yr, W2h, W2l, bf, out);
}

// Round 4
// 245.752 us; speedup vs baseline: 1.3125x; 1.3125x over previous
//
#include <hip/hip_runtime.h>

#define N_NODES 50000
#define N_EDGES 800000
#define TOT (N_EDGES + N_NODES)

typedef __attribute__((ext_vector_type(4))) float floatx4;
typedef __attribute__((ext_vector_type(8))) _Float16 half8;
typedef __attribute__((ext_vector_type(2))) _Float16 half2v;

// ---- workspace layout (bytes, 256-aligned) ----
#define O_DEG   0UL          // int[N]
#define O_PTR   200192UL     // int[N]
#define O_FILL  400384UL     // int[N]
#define O_BSUM  600576UL     // int[64]
#define O_BOFF  600832UL     // int[64]
#define O_FLAG  601088UL     // int[2]: [1]=indices-are-int64
#define O_DINV  601344UL     // float[N]
#define O_ESRC  801536UL     // int[TOT]
#define O_W1    4201728UL    // f16[128*128]  (transposed: [n][k])
#define O_W2    4234496UL    // f16[64*128]
#define O_XS    4250880UL    // f16[N*128]
#define O_YR    17050880UL   // f16[N*128]
// end: 29850880 bytes

// prep: deg=1 (self-loop), transpose+convert weights to f16, probe index width.
// int64 edge_index => odd 32-bit words are all zero (values < 2^31).
__global__ void k_prep(const float* __restrict__ Wg, const float* __restrict__ Wf,
                       const unsigned* __restrict__ ei_raw,
                       int* deg, _Float16* W1, _Float16* W2, int* flags) {
    int i = blockIdx.x * 256 + threadIdx.x;
    if (i < N_NODES) deg[i] = 1;
    if (i < 128 * 128) { int n = i >> 7, k = i & 127; W1[i] = (_Float16)Wg[k * 128 + n]; }
    if (i < 64 * 128)  { int n = i >> 7, k = i & 127; W2[i] = (_Float16)Wf[k * 64 + n]; }
    if (i >= 50048 && i < 50112) {            // one full wave of block 195
        int lane = i - 50048;
        unsigned w = ei_raw[2 * lane + 1];
        unsigned long long m = __ballot(w == 0u);
        if (lane == 0) flags[1] = (__popcll(m) >= 60) ? 1 : 0;
    }
}

__global__ void k_count(const int* ei, const int* flags, int* deg) {
    int e = blockIdx.x * 256 + threadIdx.x;
    if (e >= N_EDGES) return;
    int c = flags[1] ? ei[2 * (N_EDGES + e)] : ei[N_EDGES + e];
    atomicAdd(&deg[c], 1);
}

// 2-level exclusive scan over deg[N] -> ptr[N]
__global__ void k_scan1(const int* deg, int* ptr, int* bsum) {
    __shared__ int sm[256];
    int t = threadIdx.x;
    int base = blockIdx.x * 1024 + t * 4;
    int v[4]; int ts = 0;
#pragma unroll
    for (int j = 0; j < 4; ++j) { int idx = base + j; v[j] = (idx < N_NODES) ? deg[idx] : 0; ts += v[j]; }
    sm[t] = ts; __syncthreads();
    for (int off = 1; off < 256; off <<= 1) {
        int x = (t >= off) ? sm[t - off] : 0;
        __syncthreads();
        sm[t] += x;
        __syncthreads();
    }
    int run = sm[t] - ts;
#pragma unroll
    for (int j = 0; j < 4; ++j) { int idx = base + j; if (idx < N_NODES) ptr[idx] = run; run += v[j]; }
    if (t == 255) bsum[blockIdx.x] = sm[255];
}

#define NB_SCAN 49
__global__ void k_scan2(const int* bsum, int* boff) {
    int t = threadIdx.x;
    int v = (t < NB_SCAN) ? bsum[t] : 0;
    int s = v;
    for (int off = 1; off < 64; off <<= 1) {
        int x = __shfl_up(s, off);
        if (t >= off) s += x;
    }
    if (t < NB_SCAN) boff[t] = s - v;
}

__global__ void k_scan3(const int* deg, int* ptr, int* fill, float* dinv, const int* boff) {
    int i = blockIdx.x * 256 + threadIdx.x;
    if (i < N_NODES) {
        int p = ptr[i] + boff[i >> 10];
        ptr[i] = p; fill[i] = p;
        dinv[i] = rsqrtf((float)deg[i]);
    }
}

__global__ void k_scatter(const int* ei, const int* flags, int* fill, int* esrc) {
    int i = blockIdx.x * 256 + threadIdx.x;
    if (i >= TOT) return;
    int r, c;
    if (i < N_EDGES) {
        if (flags[1]) { r = ei[2 * i]; c = ei[2 * (N_EDGES + i)]; }
        else          { r = ei[i];     c = ei[N_EDGES + i]; }
    } else {
        r = c = i - N_EDGES;
    }
    int slot = atomicAdd(&fill[c], 1);
    esrc[slot] = r;
}

// xs[r][n] = f16( (h @ Wg)[r][n] * dinv[r] )   — f16 MFMA (rel err ~2^-11)
__global__ __launch_bounds__(256) void k_gemm1(const float* __restrict__ h,
                                               const _Float16* __restrict__ W1,
                                               const float* __restrict__ dinv,
                                               _Float16* __restrict__ xs) {
    int wave = threadIdx.x >> 6;
    int lane = threadIdx.x & 63;
    int rowbase = (blockIdx.x * 4 + wave) * 16;
    if (rowbase >= N_NODES) return;
    int quad = lane >> 4;
    int mrow = rowbase + (lane & 15);
    int mr = mrow < N_NODES ? mrow : N_NODES - 1;  // clamp loads; stores guarded
    half8 a[4];
#pragma unroll
    for (int kk = 0; kk < 4; ++kk) {
        const floatx4* p = (const floatx4*)(h + (size_t)mr * 128 + kk * 32 + quad * 8);
        floatx4 x0 = p[0], x1 = p[1];
        half8 t;
#pragma unroll
        for (int j = 0; j < 4; ++j) { t[j] = (_Float16)x0[j]; t[4 + j] = (_Float16)x1[j]; }
        a[kk] = t;
    }
    float dv[4];
#pragma unroll
    for (int i = 0; i < 4; ++i) {
        int r = rowbase + quad * 4 + i;
        dv[i] = (r < N_NODES) ? dinv[r] : 0.f;
    }
#pragma unroll
    for (int nt = 0; nt < 8; ++nt) {
        floatx4 acc = {0.f, 0.f, 0.f, 0.f};
        int n = nt * 16 + (lane & 15);
#pragma unroll
        for (int kk = 0; kk < 4; ++kk) {
            half8 b = *(const half8*)(W1 + n * 128 + kk * 32 + quad * 8);
            acc = __builtin_amdgcn_mfma_f32_16x16x32_f16(a[kk], b, acc, 0, 0, 0);
        }
#pragma unroll
        for (int i = 0; i < 4; ++i) {
            int r = rowbase + quad * 4 + i;
            if (r < N_NODES) xs[(size_t)r * 128 + n] = (_Float16)(acc[i] * dv[i]);
        }
    }
}

// one wave per node: yr[v] = f16(relu(dinv[v]*sum(xs[src]) + b_gcn))
// indices staged in registers, shfl-broadcast, 4-way unrolled for MLP.
__global__ __launch_bounds__(256) void k_agg(const _Float16* __restrict__ xs,
                                             const int* __restrict__ ptr,
                                             const int* __restrict__ esrc,
                                             const float* __restrict__ dinv,
                                             const float* __restrict__ bg,
                                             _Float16* __restrict__ yr) {
    int wid = (blockIdx.x * 256 + threadIdx.x) >> 6;
    int lane = threadIdx.x & 63;
    if (wid >= N_NODES) return;
    int p0 = ptr[wid];
    int p1 = (wid + 1 < N_NODES) ? ptr[wid + 1] : TOT;
    float a0 = 0.f, a1 = 0.f;
    for (int base = p0; base < p1; base += 64) {
        int cnt = p1 - base; if (cnt > 64) cnt = 64;
        int idx = 0;
        if (lane < cnt) idx = esrc[base + lane];
        int j = 0;
        for (; j + 4 <= cnt; j += 4) {
            int s0 = __shfl(idx, j);
            int s1 = __shfl(idx, j + 1);
            int s2 = __shfl(idx, j + 2);
            int s3 = __shfl(idx, j + 3);
            half2v u0 = *(const half2v*)(xs + (size_t)s0 * 128 + lane * 2);
            half2v u1 = *(const half2v*)(xs + (size_t)s1 * 128 + lane * 2);
            half2v u2 = *(const half2v*)(xs + (size_t)s2 * 128 + lane * 2);
            half2v u3 = *(const half2v*)(xs + (size_t)s3 * 128 + lane * 2);
            a0 += (float)u0[0] + (float)u1[0] + (float)u2[0] + (float)u3[0];
            a1 += (float)u0[1] + (float)u1[1] + (float)u2[1] + (float)u3[1];
        }
        for (; j < cnt; ++j) {
            int s = __shfl(idx, j);
            half2v u = *(const half2v*)(xs + (size_t)s * 128 + lane * 2);
            a0 += (float)u[0]; a1 += (float)u[1];
        }
    }
    float sc = dinv[wid];
    float r0 = fmaxf(fmaf(a0, sc, bg[lane * 2]), 0.f);
    float r1 = fmaxf(fmaf(a1, sc, bg[lane * 2 + 1]), 0.f);
    half2v o; o[0] = (_Float16)r0; o[1] = (_Float16)r1;
    *(half2v*)(yr + (size_t)wid * 128 + lane * 2) = o;
}

// out[r][n] = f32( (yr @ Wf)[r][n] + b_fc[n] )
__global__ __launch_bounds__(256) void k_gemm2(const _Float16* __restrict__ yr,
                                               const _Float16* __restrict__ W2,
                                               const float* __restrict__ bfc,
                                               float* __restrict__ out) {
    int wave = threadIdx.x >> 6;
    int lane = threadIdx.x & 63;
    int rowbase = (blockIdx.x * 4 + wave) * 16;
    if (rowbase >= N_NODES) return;
    int quad = lane >> 4;
    int mrow = rowbase + (lane & 15);
    int mr = mrow < N_NODES ? mrow : N_NODES - 1;
    half8 a[4];
#pragma unroll
    for (int kk = 0; kk < 4; ++kk)
        a[kk] = *(const half8*)(yr + (size_t)mr * 128 + kk * 32 + quad * 8);
#pragma unroll
    for (int nt = 0; nt < 4; ++nt) {
        floatx4 acc = {0.f, 0.f, 0.f, 0.f};
        int n = nt * 16 + (lane & 15);
#pragma unroll
        for (int kk = 0; kk < 4; ++kk) {
            half8 b = *(const half8*)(W2 + n * 128 + kk * 32 + quad * 8);
            acc = __builtin_amdgcn_mfma_f32_16x16x32_f16(a[kk], b, acc, 0, 0, 0);
        }
        float bias = bfc[n];
#pragma unroll
        for (int i = 0; i < 4; ++i) {
            int r = rowbase + quad * 4 + i;
            if (r < N_NODES) out[(size_t)r * 64 + n] = acc[i] + bias;
        }
    }
}

extern "C" void kernel_launch(void* const* d_in, const int* in_sizes, int n_in,
                              void* d_out, int out_size, void* d_ws, size_t ws_size,
                              hipStream_t stream) {
    (void)in_sizes; (void)n_in; (void)out_size; (void)ws_size;
    const float* h  = (const float*)d_in[0];
    const int*   ei = (const int*)d_in[1];
    const float* Wg = (const float*)d_in[2];
    const float* bg = (const float*)d_in[3];
    const float* Wf = (const float*)d_in[4];
    const float* bf = (const float*)d_in[5];
    float* out = (float*)d_out;

    char* ws = (char*)d_ws;
    int*      deg   = (int*)(ws + O_DEG);
    int*      ptr   = (int*)(ws + O_PTR);
    int*      fill  = (int*)(ws + O_FILL);
    int*      bsum  = (int*)(ws + O_BSUM);
    int*      boff  = (int*)(ws + O_BOFF);
    int*      flags = (int*)(ws + O_FLAG);
    float*    dinv  = (float*)(ws + O_DINV);
    int*      esrc  = (int*)(ws + O_ESRC);
    _Float16* W1    = (_Float16*)(ws + O_W1);
    _Float16* W2    = (_Float16*)(ws + O_W2);
    _Float16* xs    = (_Float16*)(ws + O_XS);
    _Float16* yr    = (_Float16*)(ws + O_YR);

    k_prep<<<196, 256, 0, stream>>>(Wg, Wf, (const unsigned*)ei, deg, W1, W2, flags);
    k_count<<<(N_EDGES + 255) / 256, 256, 0, stream>>>(ei, flags, deg);
    k_scan1<<<NB_SCAN, 256, 0, stream>>>(deg, ptr, bsum);
    k_scan2<<<1, 64, 0, stream>>>(bsum, boff);
    k_scan3<<<196, 256, 0, stream>>>(deg, ptr, fill, dinv, boff);
    k_scatter<<<(TOT + 255) / 256, 256, 0, stream>>>(ei, flags, fill, esrc);
    k_gemm1<<<(N_NODES + 63) / 64, 256, 0, stream>>>(h, W1, dinv, xs);
    k_agg<<<(N_NODES + 3) / 4, 256, 0, stream>>>(xs, ptr, esrc, dinv, bg, yr);
    k_gemm2<<<(N_NODES + 63) / 64, 256, 0, stream>>>(yr, W2, bf, out);
}

// Round 5
// 177.714 us; speedup vs baseline: 1.8150x; 1.3829x over previous
//
#include <hip/hip_runtime.h>

#define N_NODES 50000
#define N_EDGES 800000
#define TOT (N_EDGES + N_NODES)
#define NBKT 196          // dest buckets of 256 nodes
#define BCAP 6144         // staging capacity per bucket (mean 4096 + 32 sigma)

typedef __attribute__((ext_vector_type(4))) float floatx4;
typedef __attribute__((ext_vector_type(8))) _Float16 half8;
typedef __attribute__((ext_vector_type(2))) _Float16 half2v;

// ---- workspace layout (bytes) ----
#define O_PTR   0UL          // int[N]
#define O_GF    200192UL     // int[NBKT] bucket fill/totals
#define O_CB    201216UL     // int[256]  bucket CSR base (excl scan)
#define O_FLAG  202240UL     // int[2]: [1]=indices-are-int64
#define O_DINV  202496UL     // float[N]
#define O_ESRC  402688UL     // int[TOT]
#define O_W1    3802880UL    // f16[128*128] (transposed [n][k])
#define O_W2    3835648UL    // f16[64*128]
#define O_XS    3852032UL    // f16[N*128]; ALIASED: u32 staging[NBKT*BCAP] (dead before gemm1)
#define O_YR    16652032UL   // f16[N*128]
// end: 29452032 bytes (<= 29.9MB proven footprint)

// prep: transpose+convert weights to f16, zero bucket fills, probe index width.
// int64 edge_index => odd 32-bit words are all zero (values < 2^31).
__global__ void k_prep(const float* __restrict__ Wg, const float* __restrict__ Wf,
                       const unsigned* __restrict__ ei_raw,
                       int* gfill, _Float16* W1, _Float16* W2, int* flags) {
    int i = blockIdx.x * 256 + threadIdx.x;
    if (i < 128 * 128) { int n = i >> 7, k = i & 127; W1[i] = (_Float16)Wg[k * 128 + n]; }
    if (i < 64 * 128)  { int n = i >> 7, k = i & 127; W2[i] = (_Float16)Wf[k * 64 + n]; }
    if (i < NBKT) gfill[i] = 0;
    if (i >= 16320) {                         // last wave of block 63
        int lane = i - 16320;
        unsigned w = ei_raw[2 * lane + 1];
        unsigned long long m = __ballot(w == 0u);
        if (lane == 0) flags[1] = (__popcll(m) >= 60) ? 1 : 0;
    }
}

// Pass A: coarse-bin edges by dest>>8 into per-bucket staging runs.
__global__ __launch_bounds__(256) void k_binA(const int* __restrict__ ei,
                                              const int* __restrict__ flags,
                                              int* __restrict__ gfill,
                                              unsigned* __restrict__ staging) {
    __shared__ int cnt[NBKT];
    __shared__ int gbase[NBKT];
    int t = threadIdx.x;
    for (int i = t; i < NBKT; i += 256) cnt[i] = 0;
    __syncthreads();
    int ebase = blockIdx.x * 4096;
    bool i64 = flags[1] != 0;
    unsigned pk[16]; int rk[16]; short bk[16];
#pragma unroll
    for (int j = 0; j < 16; ++j) {
        int e = ebase + j * 256 + t;
        if (e < N_EDGES) {
            int s, d;
            if (i64) { s = ei[2 * e]; d = ei[2 * (N_EDGES + e)]; }
            else     { s = ei[e];     d = ei[N_EDGES + e]; }
            int b = d >> 8;
            bk[j] = (short)b;
            pk[j] = (unsigned)s | ((unsigned)(d & 255) << 16);
            rk[j] = atomicAdd(&cnt[b], 1);
        } else bk[j] = -1;
    }
    __syncthreads();
    for (int i = t; i < NBKT; i += 256)
        gbase[i] = atomicAdd(&gfill[i], cnt[i]);
    __syncthreads();
#pragma unroll
    for (int j = 0; j < 16; ++j) {
        if (bk[j] >= 0) {
            int pos = gbase[bk[j]] + rk[j];
            if (pos < BCAP) staging[(size_t)bk[j] * BCAP + pos] = pk[j];
        }
    }
}

// exclusive scan over (bucket_count + nodes_in_bucket) -> CSR base per bucket
__global__ void k_scanB(const int* __restrict__ gfill, int* __restrict__ cbase) {
    __shared__ int sm[256];
    int t = threadIdx.x;
    int nn = (t < NBKT) ? ((t == NBKT - 1) ? (N_NODES - 256 * (NBKT - 1)) : 256) : 0;
    int v = (t < NBKT) ? (gfill[t] + nn) : 0;
    sm[t] = v; __syncthreads();
    for (int off = 1; off < 256; off <<= 1) {
        int x = (t >= off) ? sm[t - off] : 0;
        __syncthreads(); sm[t] += x; __syncthreads();
    }
    if (t < NBKT) cbase[t] = sm[t] - v;
}

// Pass B: per bucket, exact CSR + ptr + dinv. Self-loop first in each segment.
__global__ __launch_bounds__(256) void k_binB(const unsigned* __restrict__ staging,
                                              const int* __restrict__ gfill,
                                              const int* __restrict__ cbase,
                                              int* __restrict__ ptr,
                                              float* __restrict__ dinv,
                                              int* __restrict__ esrc) {
    __shared__ int lcnt[256];
    __shared__ int lscan[256];
    __shared__ int cur[256];
    int b = blockIdx.x;
    int t = threadIdx.x;
    int nbase = b * 256;
    int nn = min(256, N_NODES - nbase);
    int cnt = min(gfill[b], BCAP);
    int cb = cbase[b];
    const unsigned* st = staging + (size_t)b * BCAP;
    lcnt[t] = 0;
    __syncthreads();
    for (int i = t; i < cnt; i += 256)
        atomicAdd(&lcnt[st[i] >> 16], 1);
    __syncthreads();
    int v = lcnt[t];
    lscan[t] = v;
    __syncthreads();
    for (int off = 1; off < 256; off <<= 1) {
        int x = (t >= off) ? lscan[t - off] : 0;
        __syncthreads(); lscan[t] += x; __syncthreads();
    }
    // node t: edges before it within bucket = lscan[t]-v; plus t self-loops
    int segstart = cb + (lscan[t] - v) + t;
    if (t < nn) {
        int node = nbase + t;
        ptr[node] = segstart;
        dinv[node] = rsqrtf((float)(v + 1));
        esrc[segstart] = node;             // self-loop entry
        cur[t] = segstart + 1;
    }
    __syncthreads();
    for (int i = t; i < cnt; i += 256) {
        unsigned p = st[i];
        int pos = atomicAdd(&cur[p >> 16], 1);
        esrc[pos] = (int)(p & 0xffffu);
    }
}

// xs[r][n] = f16( (h @ Wg)[r][n] * dinv[r] )   — f16 MFMA (rel err ~2^-11)
__global__ __launch_bounds__(256) void k_gemm1(const float* __restrict__ h,
                                               const _Float16* __restrict__ W1,
                                               const float* __restrict__ dinv,
                                               _Float16* __restrict__ xs) {
    int wave = threadIdx.x >> 6;
    int lane = threadIdx.x & 63;
    int rowbase = (blockIdx.x * 4 + wave) * 16;
    if (rowbase >= N_NODES) return;
    int quad = lane >> 4;
    int mrow = rowbase + (lane & 15);
    int mr = mrow < N_NODES ? mrow : N_NODES - 1;  // clamp loads; stores guarded
    half8 a[4];
#pragma unroll
    for (int kk = 0; kk < 4; ++kk) {
        const floatx4* p = (const floatx4*)(h + (size_t)mr * 128 + kk * 32 + quad * 8);
        floatx4 x0 = p[0], x1 = p[1];
        half8 tt;
#pragma unroll
        for (int j = 0; j < 4; ++j) { tt[j] = (_Float16)x0[j]; tt[4 + j] = (_Float16)x1[j]; }
        a[kk] = tt;
    }
    float dv[4];
#pragma unroll
    for (int i = 0; i < 4; ++i) {
        int r = rowbase + quad * 4 + i;
        dv[i] = (r < N_NODES) ? dinv[r] : 0.f;
    }
#pragma unroll
    for (int nt = 0; nt < 8; ++nt) {
        floatx4 acc = {0.f, 0.f, 0.f, 0.f};
        int n = nt * 16 + (lane & 15);
#pragma unroll
        for (int kk = 0; kk < 4; ++kk) {
            half8 bb = *(const half8*)(W1 + n * 128 + kk * 32 + quad * 8);
            acc = __builtin_amdgcn_mfma_f32_16x16x32_f16(a[kk], bb, acc, 0, 0, 0);
        }
#pragma unroll
        for (int i = 0; i < 4; ++i) {
            int r = rowbase + quad * 4 + i;
            if (r < N_NODES) xs[(size_t)r * 128 + n] = (_Float16)(acc[i] * dv[i]);
        }
    }
}

// one wave per node: yr[v] = f16(relu(dinv[v]*sum(xs[src]) + b_gcn))
__global__ __launch_bounds__(256) void k_agg(const _Float16* __restrict__ xs,
                                             const int* __restrict__ ptr,
                                             const int* __restrict__ esrc,
                                             const float* __restrict__ dinv,
                                             const float* __restrict__ bg,
                                             _Float16* __restrict__ yr) {
    int wid = (blockIdx.x * 256 + threadIdx.x) >> 6;
    int lane = threadIdx.x & 63;
    if (wid >= N_NODES) return;
    int p0 = ptr[wid];
    int p1 = (wid + 1 < N_NODES) ? ptr[wid + 1] : TOT;
    float a0 = 0.f, a1 = 0.f;
    for (int base = p0; base < p1; base += 64) {
        int cnt = p1 - base; if (cnt > 64) cnt = 64;
        int idx = 0;
        if (lane < cnt) idx = esrc[base + lane];
        int j = 0;
        for (; j + 4 <= cnt; j += 4) {
            int s0 = __shfl(idx, j);
            int s1 = __shfl(idx, j + 1);
            int s2 = __shfl(idx, j + 2);
            int s3 = __shfl(idx, j + 3);
            half2v u0 = *(const half2v*)(xs + (size_t)s0 * 128 + lane * 2);
            half2v u1 = *(const half2v*)(xs + (size_t)s1 * 128 + lane * 2);
            half2v u2 = *(const half2v*)(xs + (size_t)s2 * 128 + lane * 2);
            half2v u3 = *(const half2v*)(xs + (size_t)s3 * 128 + lane * 2);
            a0 += (float)u0[0] + (float)u1[0] + (float)u2[0] + (float)u3[0];
            a1 += (float)u0[1] + (float)u1[1] + (float)u2[1] + (float)u3[1];
        }
        for (; j < cnt; ++j) {
            int s = __shfl(idx, j);
            half2v u = *(const half2v*)(xs + (size_t)s * 128 + lane * 2);
            a0 += (float)u[0]; a1 += (float)u[1];
        }
    }
    float sc = dinv[wid];
    float r0 = fmaxf(fmaf(a0, sc, bg[lane * 2]), 0.f);
    float r1 = fmaxf(fmaf(a1, sc, bg[lane * 2 + 1]), 0.f);
    half2v o; o[0] = (_Float16)r0; o[1] = (_Float16)r1;
    *(half2v*)(yr + (size_t)wid * 128 + lane * 2) = o;
}

// out[r][n] = f32( (yr @ Wf)[r][n] + b_fc[n] )
__global__ __launch_bounds__(256) void k_gemm2(const _Float16* __restrict__ yr,
                                               const _Float16* __restrict__ W2,
                                               const float* __restrict__ bfc,
                                               float* __restrict__ out) {
    int wave = threadIdx.x >> 6;
    int lane = threadIdx.x & 63;
    int rowbase = (blockIdx.x * 4 + wave) * 16;
    if (rowbase >= N_NODES) return;
    int quad = lane >> 4;
    int mrow = rowbase + (lane & 15);
    int mr = mrow < N_NODES ? mrow : N_NODES - 1;
    half8 a[4];
#pragma unroll
    for (int kk = 0; kk < 4; ++kk)
        a[kk] = *(const half8*)(yr + (size_t)mr * 128 + kk * 32 + quad * 8);
#pragma unroll
    for (int nt = 0; nt < 4; ++nt) {
        floatx4 acc = {0.f, 0.f, 0.f, 0.f};
        int n = nt * 16 + (lane & 15);
#pragma unroll
        for (int kk = 0; kk < 4; ++kk) {
            half8 bb = *(const half8*)(W2 + n * 128 + kk * 32 + quad * 8);
            acc = __builtin_amdgcn_mfma_f32_16x16x32_f16(a[kk], bb, acc, 0, 0, 0);
        }
        float bias = bfc[n];
#pragma unroll
        for (int i = 0; i < 4; ++i) {
            int r = rowbase + quad * 4 + i;
            if (r < N_NODES) out[(size_t)r * 64 + n] = acc[i] + bias;
        }
    }
}

extern "C" void kernel_launch(void* const* d_in, const int* in_sizes, int n_in,
                              void* d_out, int out_size, void* d_ws, size_t ws_size,
                              hipStream_t stream) {
    (void)in_sizes; (void)n_in; (void)out_size; (void)ws_size;
    const float* h  = (const float*)d_in[0];
    const int*   ei = (const int*)d_in[1];
    const float* Wg = (const float*)d_in[2];
    const float* bg = (const float*)d_in[3];
    const float* Wf = (const float*)d_in[4];
    const float* bf = (const float*)d_in[5];
    float* out = (float*)d_out;

    char* ws = (char*)d_ws;
    int*      ptr   = (int*)(ws + O_PTR);
    int*      gfill = (int*)(ws + O_GF);
    int*      cbase = (int*)(ws + O_CB);
    int*      flags = (int*)(ws + O_FLAG);
    float*    dinv  = (float*)(ws + O_DINV);
    int*      esrc  = (int*)(ws + O_ESRC);
    _Float16* W1    = (_Float16*)(ws + O_W1);
    _Float16* W2    = (_Float16*)(ws + O_W2);
    _Float16* xs    = (_Float16*)(ws + O_XS);
    _Float16* yr    = (_Float16*)(ws + O_YR);
    unsigned* staging = (unsigned*)(ws + O_XS);   // aliased; dead before gemm1

    k_prep<<<64, 256, 0, stream>>>(Wg, Wf, (const unsigned*)ei, gfill, W1, W2, flags);
    k_binA<<<NBKT, 256, 0, stream>>>(ei, flags, gfill, staging);
    k_scanB<<<1, 256, 0, stream>>>(gfill, cbase);
    k_binB<<<NBKT, 256, 0, stream>>>(staging, gfill, cbase, ptr, dinv, esrc);
    k_gemm1<<<(N_NODES + 63) / 64, 256, 0, stream>>>(h, W1, dinv, xs);
    k_agg<<<(N_NODES + 3) / 4, 256, 0, stream>>>(xs, ptr, esrc, dinv, bg, yr);
    k_gemm2<<<(N_NODES + 63) / 64, 256, 0, stream>>>(yr, W2, bf, out);
}